// Round 1
// baseline (37.889 us; speedup 1.0000x reference)
//
#include <hip/hip_runtime.h>
#include <hip/hip_bf16.h>

// Conv encoder, rate 1/2, constraint length 3, GEN_POLY = ("101", "111").
// State s = [u[t-1], u[t-2]]; out_table reduces to:
//   c0[t] = u[t] ^ u[t-2]            (poly "101")
//   c1[t] = u[t] ^ u[t-1] ^ u[t-2]   (poly "111")
// with u[-1] = u[-2] = 0.  Output interleaved: out[b, 2t] = c0, out[b, 2t+1] = c1.
// Fully parallel, memory-bound (64 MB read + 128 MB write).

__global__ void conv_enc_kernel(const float* __restrict__ in,
                                float* __restrict__ out,
                                int B, int K) {
    // Each thread: 4 consecutive time steps of one row.
    const int perRow = K >> 2;                       // K/4 threads per row
    long tid = (long)blockIdx.x * blockDim.x + threadIdx.x;
    long total = (long)B * perRow;
    if (tid >= total) return;

    int b  = (int)(tid / perRow);
    int i  = (int)(tid % perRow);
    int t0 = i << 2;

    const float* rowIn = in + (long)b * K;
    float4 v = *reinterpret_cast<const float4*>(rowIn + t0);

    // Two lookback bits (L1-hit scalar loads; zero at the row start).
    float pm1 = (t0 >= 1) ? rowIn[t0 - 1] : 0.0f;    // u[t0-1]
    float pm2 = (t0 >= 2) ? rowIn[t0 - 2] : 0.0f;    // u[t0-2]

    int u0 = (int)v.x, u1 = (int)v.y, u2 = (int)v.z, u3 = (int)v.w;
    int p1 = (int)pm1, p2 = (int)pm2;

    // t = t0   : (u[t],u[t-1],u[t-2]) = (u0, p1, p2)
    // t = t0+1 :                        (u1, u0, p1)
    // t = t0+2 :                        (u2, u1, u0)
    // t = t0+3 :                        (u3, u2, u1)
    int c00 = u0 ^ p2,  c10 = u0 ^ p1 ^ p2;
    int c01 = u1 ^ p1,  c11 = u1 ^ u0 ^ p1;
    int c02 = u2 ^ u0,  c12 = u2 ^ u1 ^ u0;
    int c03 = u3 ^ u1,  c13 = u3 ^ u2 ^ u1;

    float4 o0 = make_float4((float)c00, (float)c10, (float)c01, (float)c11);
    float4 o1 = make_float4((float)c02, (float)c12, (float)c03, (float)c13);

    float4* rowOut = reinterpret_cast<float4*>(out + (long)b * (2 * K) + (t0 << 1));
    rowOut[0] = o0;
    rowOut[1] = o1;
}

extern "C" void kernel_launch(void* const* d_in, const int* in_sizes, int n_in,
                              void* d_out, int out_size, void* d_ws, size_t ws_size,
                              hipStream_t stream) {
    const float* in = (const float*)d_in[0];
    float* out = (float*)d_out;

    const int B = 8192;
    const int K = 2048;           // in_sizes[0] == B*K
    const int perRow = K / 4;
    long total = (long)B * perRow;          // 4,194,304 threads
    int block = 256;
    int grid = (int)((total + block - 1) / block);

    conv_enc_kernel<<<grid, block, 0, stream>>>(in, out, B, K);
}